// Round 2
// baseline (85.529 us; speedup 1.0000x reference)
//
#include <hip/hip_runtime.h>
#include <math.h>

// Problem constants
#define BATCH 32
#define SEQ   512
#define DIN   512
#define IFACE 919
#define TAILC 274     // iface columns 645..918 are the only ones used
#define TAIL0 645

// ws float offsets
#define XM_PART 0        // 32*16*512 = 262144 (partial seq sums, 16 chunks/batch)
#define EVO     262144   // 32*128 sigmoid(erase)
#define WVO     266240   // 32*128 write vector
#define WWH     270336   // 32*64  ww for n<64
#define SCAL    272384   // 32*2   [u, wwc]

// d_out float offsets (tuple concat: out, memory, link, usage, prec, ww, rw)
#define OUT_OFF   0
#define MEM_OFF   16384
#define LINK_OFF  4210688      // 32*1024*1024 floats of exact zeros
#define USAGE_OFF 37765120
#define PREC_OFF  37797888
#define WW_OFF    37830656
#define RW_OFF    37863424

#define LINK4     8388608      // 33554432 / 4 float4s
#define ZBLOCKS   4096
#define RBLOCKS   512

__device__ __forceinline__ float sigmoidf_(float x) { return 1.0f / (1.0f + expf(-x)); }

// KA: blocks [0,512): partial reduce of x over seq; blocks [512, 512+4096): zero link.
__global__ void kA(const float* __restrict__ x, float* __restrict__ ws,
                   float4* __restrict__ link) {
    int bid = blockIdx.x;
    if (bid < RBLOCKS) {
        int b = bid >> 4, c = bid & 15, t = threadIdx.x;
        int half = t >> 7, d4 = t & 127;
        __shared__ float4 tmp[128];
        const float4* xr = (const float4*)(x + (size_t)((b * SEQ) + c * 32 + half * 16) * DIN);
        float4 acc = {0.f, 0.f, 0.f, 0.f};
        #pragma unroll
        for (int s = 0; s < 16; ++s) {
            float4 v = xr[s * 128 + d4];
            acc.x += v.x; acc.y += v.y; acc.z += v.z; acc.w += v.w;
        }
        if (half == 1) tmp[d4] = acc;
        __syncthreads();
        if (half == 0) {
            float4 o = tmp[d4];
            acc.x += o.x; acc.y += o.y; acc.z += o.z; acc.w += o.w;
            ((float4*)(ws + XM_PART))[(b * 16 + c) * 128 + d4] = acc;
        }
    } else {
        int idx = (bid - RBLOCKS) * 256 + threadIdx.x;
        int stride = ZBLOCKS * 256;
        float4 z = {0.f, 0.f, 0.f, 0.f};
        for (int i = idx; i < LINK4; i += stride) link[i] = z;
    }
}

// KB: one block per batch. Finish reduce -> GEMV -> params -> small outputs.
__global__ void kB(float* __restrict__ ws, const float* __restrict__ Wif,
                   float* __restrict__ out) {
    __shared__ float xms[DIN];
    __shared__ float p[TAILC];
    __shared__ float s_u, s_wwc, s_wwh[64];
    int b = blockIdx.x, t = threadIdx.x;

    for (int d = t; d < DIN; d += 256) {
        const float* q = ws + XM_PART + (size_t)b * 16 * DIN + d;
        float s = 0.f;
        #pragma unroll
        for (int c = 0; c < 16; ++c) s += q[c * DIN];
        xms[d] = s;
    }
    __syncthreads();

    for (int j = t; j < TAILC; j += 256) {
        const float* wcol = Wif + TAIL0 + j;
        float acc = 0.f;
        #pragma unroll 8
        for (int k = 0; k < DIN; ++k) acc += xms[k] * wcol[(size_t)k * IFACE];
        p[j] = acc * (1.0f / SEQ);
    }
    __syncthreads();

    // read_modes softmax, middle mode (redundant per thread, reads shared p)
    float rm1[4];
    #pragma unroll
    for (int r = 0; r < 4; ++r) {
        float i0 = p[262 + r], i1 = p[266 + r], i2 = p[270 + r];
        float mx = fmaxf(i0, fmaxf(i1, i2));
        float e0 = expf(i0 - mx), e1 = expf(i1 - mx), e2 = expf(i2 - mx);
        rm1[r] = e1 / (e0 + e1 + e2);
    }

    if (t < 128) {
        ws[EVO + b * 128 + t] = sigmoidf_(p[t]);
        ws[WVO + b * 128 + t] = p[128 + t];
        float4 o = {1e-6f * rm1[0], 1e-6f * rm1[1], 1e-6f * rm1[2], 1e-6f * rm1[3]};
        ((float4*)(out + OUT_OFF))[b * 128 + t] = o;
    }

    if (t == 0) {
        const float inv1024 = 1.0f / 1024.0f;
        float ret = 1.f;
        #pragma unroll
        for (int r = 0; r < 4; ++r) {
            float fg = sigmoidf_(p[256 + r]);
            ret *= (1.f - fg * rm1[r] * inv1024);
        }
        float u = 1e-6f * ret;
        float ag = sigmoidf_(p[260]);
        float wg = sigmoidf_(p[261]);
        float wwc = wg * (1.f - ag) * inv1024;     // ww for n >= 64 (alloc underflowed)
        s_u = u; s_wwc = wwc;
        ws[SCAL + b * 2 + 0] = u;
        ws[SCAL + b * 2 + 1] = wwc;
        float cum = 1.f;
        for (int n = 0; n < 64; ++n) {             // same f32 cumprod as reference
            float alloc = (1.f - u) * cum;
            float w = wg * (ag * alloc + (1.f - ag) * inv1024);
            s_wwh[n] = w;
            ws[WWH + b * 64 + n] = w;
            cum *= u;
        }
    }
    __syncthreads();

    float u = s_u;
    float4 rv = {rm1[0] * (1.0f / 1024.0f), rm1[1] * (1.0f / 1024.0f),
                 rm1[2] * (1.0f / 1024.0f), rm1[3] * (1.0f / 1024.0f)};
    for (int n = t; n < 1024; n += 256) {
        float ww = (n < 64) ? s_wwh[n] : s_wwc;
        out[USAGE_OFF + b * 1024 + n] = u;
        out[PREC_OFF + b * 1024 + n] = ww;   // prec = ww (prec0 = 0)
        out[WW_OFF + b * 1024 + n] = ww;
        ((float4*)out)[RW_OFF / 4 + b * 1024 + n] = rv;
    }
}

// KC: memory fill, 4096 blocks x 256 threads, float4 per thread (16.8 MB write)
__global__ void kC(const float* __restrict__ ws, float* __restrict__ out) {
    int idx = blockIdx.x * 256 + threadIdx.x;   // < 1048576 float4
    int w4 = idx & 31;
    int n  = (idx >> 5) & 1023;
    int b  = idx >> 15;
    float ww = (n < 64) ? ws[WWH + b * 64 + n] : ws[SCAL + b * 2 + 1];
    float4 e = ((const float4*)(ws + EVO))[b * 32 + w4];
    float4 v = ((const float4*)(ws + WVO))[b * 32 + w4];
    float4 m;
    m.x = 1e-6f * (1.f - ww * e.x) + ww * v.x;
    m.y = 1e-6f * (1.f - ww * e.y) + ww * v.y;
    m.z = 1e-6f * (1.f - ww * e.z) + ww * v.z;
    m.w = 1e-6f * (1.f - ww * e.w) + ww * v.w;
    ((float4*)(out + MEM_OFF))[idx] = m;
}

extern "C" void kernel_launch(void* const* d_in, const int* in_sizes, int n_in,
                              void* d_out, int out_size, void* d_ws, size_t ws_size,
                              hipStream_t stream) {
    const float* x   = (const float*)d_in[0];
    const float* Wif = (const float*)d_in[1];
    float* out = (float*)d_out;
    float* ws  = (float*)d_ws;

    kA<<<RBLOCKS + ZBLOCKS, 256, 0, stream>>>(x, ws, (float4*)(out + LINK_OFF));
    kB<<<32, 256, 0, stream>>>(ws, Wif, out);
    kC<<<4096, 256, 0, stream>>>(ws, out);
}

// Round 3
// 63.137 us; speedup vs baseline: 1.3547x; 1.3547x over previous
//
#include <hip/hip_runtime.h>
#include <math.h>

// Problem constants
#define BATCH 32
#define SEQ   512
#define DIN   512
#define IFACE 919
#define TAILC 274     // iface columns 645..918 are the only ones used
#define TAIL0 645

// ws float offsets
#define XM_PART 0        // 32*16*512 = 262144 (partial seq sums, 16 chunks/batch)
#define EVO     262144   // 32*128 sigmoid(erase)
#define WVO     266240   // 32*128 write vector
#define WWH     270336   // 32*64  ww for n<64
#define SCAL    272384   // 32*2   [u, wwc]
#define RWV     272448   // 32*4   rw per head

// d_out float offsets (tuple concat: out, memory, link, usage, prec, ww, rw)
#define OUT_OFF   0
#define MEM_OFF   16384
#define LINK_OFF  4210688      // 32*1024*1024 floats of exact zeros
#define USAGE_OFF 37765120
#define PREC_OFF  37797888
#define WW_OFF    37830656
#define RW_OFF    37863424

__device__ __forceinline__ float sigmoidf_(float x) { return 1.0f / (1.0f + expf(-x)); }

// K1: partial reduce of x over seq. grid (16 chunks, 32 batch), 128 threads (float4/lane)
__global__ void k_reduce_x(const float* __restrict__ x, float* __restrict__ ws) {
    int c = blockIdx.x, b = blockIdx.y, t = threadIdx.x;
    const float4* xr = (const float4*)(x + (size_t)(b * SEQ + c * 32) * DIN);
    float4 acc = {0.f, 0.f, 0.f, 0.f};
    for (int s = 0; s < 32; ++s) {
        float4 v = xr[s * 128 + t];
        acc.x += v.x; acc.y += v.y; acc.z += v.z; acc.w += v.w;
    }
    ((float4*)(ws + XM_PART))[(b * 16 + c) * 128 + t] = acc;
}

// K2: one block per batch, 512 threads. Finish reduce -> GEMV (1 col/thread) -> params.
__global__ __launch_bounds__(512) void kB(float* __restrict__ ws,
                                          const float* __restrict__ Wif,
                                          float* __restrict__ out) {
    __shared__ float xms[DIN];
    __shared__ float p[TAILC];
    int b = blockIdx.x, t = threadIdx.x;

    {   // finish the two-stage reduce: sum 16 partials for dim t
        const float* q = ws + XM_PART + (size_t)b * 16 * DIN + t;
        float s = 0.f;
        #pragma unroll
        for (int c = 0; c < 16; ++c) s += q[c * DIN];
        xms[t] = s;
    }
    __syncthreads();

    if (t < TAILC) {   // GEMV: one column per thread
        const float* wcol = Wif + TAIL0 + t;
        float acc = 0.f;
        #pragma unroll 8
        for (int k = 0; k < DIN; ++k) acc += xms[k] * wcol[(size_t)k * IFACE];
        p[t] = acc * (1.0f / SEQ);
    }
    __syncthreads();

    // read_modes softmax, middle mode (redundant per thread, reads shared p)
    float rm1[4];
    #pragma unroll
    for (int r = 0; r < 4; ++r) {
        float i0 = p[262 + r], i1 = p[266 + r], i2 = p[270 + r];
        float mx = fmaxf(i0, fmaxf(i1, i2));
        float e0 = expf(i0 - mx), e1 = expf(i1 - mx), e2 = expf(i2 - mx);
        rm1[r] = e1 / (e0 + e1 + e2);
    }

    if (t < 128) {
        ws[EVO + b * 128 + t] = sigmoidf_(p[t]);          // sigmoid(erase)
        ws[WVO + b * 128 + t] = p[128 + t];               // write vector
        // out[b, w*4+r] = 1e-6 * read_modes[1][r]  (read_vectors collapse)
        float4 o = {1e-6f * rm1[0], 1e-6f * rm1[1], 1e-6f * rm1[2], 1e-6f * rm1[3]};
        ((float4*)(out + OUT_OFF))[b * 128 + t] = o;
    }

    if (t == 0) {
        const float inv1024 = 1.0f / 1024.0f;
        float ret = 1.f;
        #pragma unroll
        for (int r = 0; r < 4; ++r) {
            ws[RWV + b * 4 + r] = rm1[r] * inv1024;       // rw value per head
            float fg = sigmoidf_(p[256 + r]);
            ret *= (1.f - fg * rm1[r] * inv1024);
        }
        float u = 1e-6f * ret;                            // usage (constant over n)
        float ag = sigmoidf_(p[260]);
        float wg = sigmoidf_(p[261]);
        ws[SCAL + b * 2 + 0] = u;
        ws[SCAL + b * 2 + 1] = wg * (1.f - ag) * inv1024; // ww for n>=64 (alloc underflowed)
        float cum = 1.f;                                  // same f32 cumprod as reference
        for (int n = 0; n < 64; ++n) {
            float alloc = (1.f - u) * cum;
            ws[WWH + b * 64 + n] = wg * (ag * alloc + (1.f - ag) * inv1024);
            cum *= u;
        }
    }
}

// K3: blocks [0,4096): memory fill (float4/thread); [4096,4224): small outputs.
__global__ void kC(const float* __restrict__ ws, float* __restrict__ out) {
    int bid = blockIdx.x;
    if (bid < 4096) {
        int idx = bid * 256 + threadIdx.x;   // < 1048576 float4
        int w4 = idx & 31;
        int n  = (idx >> 5) & 1023;
        int b  = idx >> 15;
        float ww = (n < 64) ? ws[WWH + b * 64 + n] : ws[SCAL + b * 2 + 1];
        float4 e = ((const float4*)(ws + EVO))[b * 32 + w4];
        float4 v = ((const float4*)(ws + WVO))[b * 32 + w4];
        float4 m;
        m.x = 1e-6f * (1.f - ww * e.x) + ww * v.x;
        m.y = 1e-6f * (1.f - ww * e.y) + ww * v.y;
        m.z = 1e-6f * (1.f - ww * e.z) + ww * v.z;
        m.w = 1e-6f * (1.f - ww * e.w) + ww * v.w;
        ((float4*)(out + MEM_OFF))[idx] = m;
    } else {
        int t2 = (bid - 4096) * 256 + threadIdx.x;   // < 32768
        int b = t2 >> 10, n = t2 & 1023;
        float u  = ws[SCAL + b * 2 + 0];
        float ww = (n < 64) ? ws[WWH + b * 64 + n] : ws[SCAL + b * 2 + 1];
        out[USAGE_OFF + t2] = u;
        out[PREC_OFF + t2]  = ww;   // prec = ww (prec0 = 0)
        out[WW_OFF + t2]    = ww;
        float4 rv = ((const float4*)(ws + RWV))[b];
        ((float4*)out)[RW_OFF / 4 + t2] = rv;   // rw[b,n,:] constant over n
    }
}

extern "C" void kernel_launch(void* const* d_in, const int* in_sizes, int n_in,
                              void* d_out, int out_size, void* d_ws, size_t ws_size,
                              hipStream_t stream) {
    const float* x   = (const float*)d_in[0];
    const float* Wif = (const float*)d_in[1];
    float* out = (float*)d_out;
    float* ws  = (float*)d_ws;

    // link output is exactly zero (link0 = 0, prec0 = 0): runtime fill @ ~7 TB/s
    hipMemsetAsync(out + LINK_OFF, 0, 33554432ull * sizeof(float), stream);
    k_reduce_x<<<dim3(16, 32), 128, 0, stream>>>(x, ws);
    kB<<<32, 512, 0, stream>>>(ws, Wif, out);
    kC<<<4224, 256, 0, stream>>>(ws, out);
}